// Round 7
// baseline (202.377 us; speedup 1.0000x reference)
//
#include <hip/hip_runtime.h>
#include <hip/hip_bf16.h>
#include <math.h>

// Problem dims (fixed by the reference)
#define B_  64
#define S_  512
#define D_  1024
#define E2_ 1024
#define WROW (D_ + E2_)   // 2048, row stride of w_weight
#define NTILES 4          // D_ / BNE (256-wide n-tiles)

typedef __attribute__((ext_vector_type(8))) short bf16x8;
typedef __attribute__((ext_vector_type(4))) float f32x4;
typedef __attribute__((ext_vector_type(8))) unsigned short u16x8;

// round-to-nearest-even f32 -> bf16
__device__ __forceinline__ unsigned short f2bf(float f) {
    unsigned u = __float_as_uint(f);
    u = (u + 0x7FFFu + ((u >> 16) & 1u)) >> 16;
    return (unsigned short)u;
}

__device__ __forceinline__ void load_lds16(const void* g, void* l) {
    __builtin_amdgcn_global_load_lds(
        (__attribute__((address_space(1))) void*)(void*)g,
        (__attribute__((address_space(3))) void*)l,
        16, 0, 0);
}

// branch-free tanh via v_exp_f32: tanh(x) = sign(x)*(e^{2|x|}-1)/(e^{2|x|}+1)
__device__ __forceinline__ float fast_tanh(float x) {
    float ax = fminf(fabsf(x), 16.0f);                       // tanh(16)==1.0f
    float t  = __builtin_amdgcn_exp2f(ax * 2.8853900817779268f); // e^{2ax}
    float r  = (t - 1.0f) * __builtin_amdgcn_rcpf(t + 1.0f);
    return copysignf(r, x);
}

// ---------------------------------------------------------------------------
// Convert We = w[:, D_:] (strided in w) -> dense bf16 (D_ x E2_)
// ---------------------------------------------------------------------------
__global__ __launch_bounds__(256) void conv_we_kernel(
        const float* __restrict__ w, unsigned short* __restrict__ web)
{
    const int k = blockIdx.x;
    const int j = threadIdx.x * 4;
    float4 a = *reinterpret_cast<const float4*>(w + (size_t)k * WROW + D_ + j);
    ushort4 o;
    o.x = f2bf(a.x); o.y = f2bf(a.y); o.z = f2bf(a.z); o.w = f2bf(a.w);
    *reinterpret_cast<ushort4*>(web + (size_t)k * E2_ + j) = o;
}

// ---------------------------------------------------------------------------
// Kernel A: t[b][k] = sum_d dec[b,d] * W[k,d] + bias[k]   (Wd = w[:, :D]), f32
// ---------------------------------------------------------------------------
__global__ __launch_bounds__(256) void dec_proj_kernel(
        const float* __restrict__ dec,    // (B, D)
        const float* __restrict__ w,      // (D, 2048)
        const float* __restrict__ bias,   // (D)
        float* __restrict__ t)            // (B, D)
{
    __shared__ float wrow[D_];
    __shared__ float red[256];
    const int k = blockIdx.x;
    const int tid = threadIdx.x;

    const float* wr = w + (size_t)k * WROW;
    for (int i = tid; i < D_; i += 256) wrow[i] = wr[i];
    __syncthreads();

    const int b = tid >> 2;
    const int q = tid & 3;
    const float* dp = dec + b * D_ + q * 256;
    const float* wp = wrow + q * 256;
    float acc = 0.f;
    #pragma unroll 8
    for (int i = 0; i < 256; ++i) acc = fmaf(dp[i], wp[i], acc);
    red[tid] = acc;
    __syncthreads();
    if (q == 0) {
        float s = red[tid] + red[tid + 1] + red[tid + 2] + red[tid + 3];
        t[b * D_ + k] = s + bias[k];
    }
}

// ---------------------------------------------------------------------------
// Kernel B: 256x256 tile, BK=64, 8 waves (2 wm x 4 wn), 512 threads.
// FUSED f32->bf16 conversion for A: per K-tile, each thread reg-loads 8x
// float4 of f32 enc (coalesced), converts, and ds_write_b64's the bf16
// directly into the SWIZZLED LDS slot (write-side swizzle; both sides
// swizzled per rule #21). B staged via global_load_lds from bf16 web.
// Loads for tile kt+1 issue BEFORE tile kt's MFMA block (T14); the
// cvt+ds_write lands after; one __syncthreads per kt orders buffer reuse.
// LDS layout: logical (row r, byte kb) at phys r*128 + (kb^((r&7)<<4)).
// XCD m-locality swizzle: 4 n-tile blocks of one m-tile -> same XCD.
// Fused epilogue: tanh + v-dot + cross-wave reduce -> att_part (B*S, 4).
// ---------------------------------------------------------------------------
#define BME 256
#define BNE 256
#define BKE 64
#define KT_ (E2_ / BKE)   // 16 K-tiles

__global__ __launch_bounds__(512, 2) void energy_mfma_kernel(
        const float* __restrict__ encf,           // (B*S, E2) f32
        const unsigned short* __restrict__ web,   // (D, E2) bf16
        const float* __restrict__ t,              // (B, D)
        const float* __restrict__ v,              // (D)
        float* __restrict__ att_part)             // (B*S, NTILES)
{
    __shared__ __align__(16) unsigned short As[2][BME * BKE];  // 2 x 32 KB
    __shared__ __align__(16) unsigned short Bs[2][BNE * BKE];  // 2 x 32 KB
    __shared__ float tv_s[BNE];
    __shared__ float vv_s[BNE];
    __shared__ float red[4][BME];

    // XCD m-locality swizzle: 512 blocks = 128 mblk x 4 ntile.
    const int g     = blockIdx.x;
    const int mblk  = (g & 7) + 8 * (g >> 5);
    const int ntile = (g >> 3) & 3;

    const int m0 = mblk * BME;
    const int n0 = ntile * BNE;
    const int b  = m0 >> 9;                 // 256-row tile never spans batches
    const int tid = threadIdx.x;
    const int w   = tid >> 6;               // wave 0..7
    const int l   = tid & 63;
    const int wm  = w >> 2;                 // wave row (0..1) -> 128 m-rows
    const int wn  = w & 3;                  // wave col (0..3) -> 64 n-cols

    if (tid < BNE) {
        tv_s[tid] = t[b * D_ + n0 + tid];
        vv_s[tid] = v[n0 + tid];
    }

    // --- A reg-staging geometry (f32 source, coalesced) ---
    // load i: row = i*32 + (tid>>4), col = (tid&15)*4  (4 f32 = one float4)
    const int arow0 = tid >> 4;              // 0..31, row&7 const across i
    const int acolb = (tid & 15) * 8;        // byte offset of col in bf16 row
    const int aswz  = (arow0 & 7) << 4;
    const float* gAf = encf + (size_t)m0 * E2_;

    // --- B staging source address (inverse-swizzled global, gload_lds) ---
    const int lr8 = l >> 3;
    const int lk  = 8 * ((l & 7) ^ lr8);
    const unsigned short* gB = web + (size_t)n0 * E2_;

    // --- frag read offsets ---
    const int rA = wm * 128 + (l & 15);
    const int rB = wn * 64 + (l & 15);
    const int kswz = (l & 7) << 4;
    const int khi  = (l >> 4) << 4;

    f32x4 acc[8][4] = {};

    // issue A f32 loads for tile kt into av[] (coalesced float4)
    float4 av[8];
    auto issueA = [&](int kt) {
        const int k0 = kt * BKE;
        #pragma unroll
        for (int i = 0; i < 8; ++i) {
            const int row = i * 32 + arow0;
            av[i] = *reinterpret_cast<const float4*>(
                gAf + (size_t)row * E2_ + k0 + (tid & 15) * 4);
        }
    };
    // issue B gload_lds for tile kt into Bs[bf]
    auto issueB = [&](int bf, int kt) {
        const int k0 = kt * BKE;
        #pragma unroll
        for (int r = 0; r < 4; ++r) {
            const int c = r * 8 + w;              // chunk 0..31
            const int row = c * 8 + lr8;          // 0..255
            load_lds16(gB + (size_t)row * E2_ + k0 + lk,
                       (char*)Bs[bf] + c * 1024);
        }
    };
    // convert av[] and write swizzled into As[bf]
    auto writeA = [&](int bf) {
        #pragma unroll
        for (int i = 0; i < 8; ++i) {
            const int row = i * 32 + arow0;
            ushort4 o;
            o.x = f2bf(av[i].x); o.y = f2bf(av[i].y);
            o.z = f2bf(av[i].z); o.w = f2bf(av[i].w);
            *reinterpret_cast<ushort4*>(
                (char*)As[bf] + row * 128 + (acolb ^ aswz)) = o;
        }
    };

    // prologue: stage tile 0
    issueA(0);
    issueB(0, 0);
    writeA(0);               // compiler inserts vmcnt wait before cvt
    __syncthreads();         // drains gload_lds + ds_write visibility

    for (int kt = 0; kt < KT_; ++kt) {
        const int cur = kt & 1;
        const int nxt = cur ^ 1;
        if (kt + 1 < KT_) {
            issueA(kt + 1);          // f32 loads fly under MFMA below
            issueB(nxt, kt + 1);     // gload_lds flies under MFMA below
        }

        #pragma unroll
        for (int kk = 0; kk < 2; ++kk) {
            const int kb = (kk * 64 + khi) ^ kswz;
            bf16x8 a[8], bb[4];
            #pragma unroll
            for (int mi = 0; mi < 8; ++mi)
                a[mi] = *reinterpret_cast<const bf16x8*>(
                    (const char*)As[cur] + (rA + mi * 16) * 128 + kb);
            #pragma unroll
            for (int ni = 0; ni < 4; ++ni)
                bb[ni] = *reinterpret_cast<const bf16x8*>(
                    (const char*)Bs[cur] + (rB + ni * 16) * 128 + kb);
            __builtin_amdgcn_s_setprio(1);
            #pragma unroll
            for (int mi = 0; mi < 8; ++mi)
                #pragma unroll
                for (int ni = 0; ni < 4; ++ni)
                    acc[mi][ni] = __builtin_amdgcn_mfma_f32_16x16x32_bf16(
                        a[mi], bb[ni], acc[mi][ni], 0, 0, 0);
            __builtin_amdgcn_s_setprio(0);
        }

        if (kt + 1 < KT_) writeA(nxt);   // cvt waits only on the f32 loads
        __syncthreads();   // drains vmcnt(gload_lds)+lgkm, orders buffer reuse
    }

    // --- epilogue: tanh + v-dot, reduce over n ---
    // D frag mapping: col = l&15, row = (l>>4)*4 + j  [m89-verified]
    #pragma unroll
    for (int mi = 0; mi < 8; ++mi) {
        float P[4] = {0.f, 0.f, 0.f, 0.f};
        #pragma unroll
        for (int ni = 0; ni < 4; ++ni) {
            const int nl = wn * 64 + ni * 16 + (l & 15);
            const float tvv = tv_s[nl];
            const float vvv = vv_s[nl];
            #pragma unroll
            for (int j = 0; j < 4; ++j) {
                float e = fast_tanh(acc[mi][ni][j] + tvv);
                P[j] = fmaf(e, vvv, P[j]);
            }
        }
        #pragma unroll
        for (int j = 0; j < 4; ++j) {
            float p = P[j];
            p += __shfl_xor(p, 1);
            p += __shfl_xor(p, 2);
            p += __shfl_xor(p, 4);
            p += __shfl_xor(p, 8);
            if ((l & 15) == 0)
                red[wn][wm * 128 + mi * 16 + (l >> 4) * 4 + j] = p;
        }
    }
    __syncthreads();
    if (tid < BME)
        att_part[(size_t)(m0 + tid) * NTILES + ntile] =
            (red[0][tid] + red[1][tid]) + (red[2][tid] + red[3][tid]);
}

// ---------------------------------------------------------------------------
// Kernel C: reduce partials + masked softmax over s per batch. One block per b.
// ---------------------------------------------------------------------------
__global__ __launch_bounds__(256) void softmax_kernel(
        const float* __restrict__ att_part,  // (B*S, NTILES)
        const int* __restrict__ mask,        // (B, S)
        float* __restrict__ wout)            // (B, S)
{
    __shared__ float red[256];
    const int b = blockIdx.x;
    const int tid = threadIdx.x;

    float x0 = 0.f, x1 = 0.f;
    #pragma unroll
    for (int p = 0; p < NTILES; ++p) {
        x0 += att_part[(size_t)(b * S_ + tid) * NTILES + p];
        x1 += att_part[(size_t)(b * S_ + 256 + tid) * NTILES + p];
    }
    bool m0v = (mask[b * S_ + tid] != 0);
    bool m1v = (mask[b * S_ + 256 + tid] != 0);
    if (!m0v) x0 = -INFINITY;
    if (!m1v) x1 = -INFINITY;

    float m = fmaxf(x0, x1);
    red[tid] = m;
    __syncthreads();
    for (int o = 128; o > 0; o >>= 1) {
        if (tid < o) red[tid] = fmaxf(red[tid], red[tid + o]);
        __syncthreads();
    }
    m = red[0];
    __syncthreads();

    float e0 = m0v ? expf(x0 - m) : 0.f;
    float e1 = m1v ? expf(x1 - m) : 0.f;
    red[tid] = e0 + e1;
    __syncthreads();
    for (int o = 128; o > 0; o >>= 1) {
        if (tid < o) red[tid] += red[tid + o];
        __syncthreads();
    }
    const float inv = 1.f / red[0];
    wout[b * S_ + tid] = e0 * inv;
    wout[b * S_ + 256 + tid] = e1 * inv;
}

// ---------------------------------------------------------------------------
// Kernel D: out_part[sc][b][e] = sum_{s in chunk sc} wgt[b,s]*enc[b,s,e]
// f32 enc, float4/lane, 8 s-chunks of 64 for occupancy; tiny reduce after.
// ---------------------------------------------------------------------------
__global__ __launch_bounds__(256) void attout_part_kernel(
        const float* __restrict__ wgt,    // (B, S)
        const float* __restrict__ enc,    // (B, S, E2) f32
        float* __restrict__ out_part)     // (8, B, E2)
{
    __shared__ float wsm[64];
    const int b  = blockIdx.y;
    const int sc = blockIdx.x;            // 0..7
    const int tid = threadIdx.x;          // e4 index, covers E2 = 256*4
    if (tid < 64) wsm[tid] = wgt[b * S_ + sc * 64 + tid];
    __syncthreads();

    const float4* ep = reinterpret_cast<const float4*>(
        enc + ((size_t)b * S_ + sc * 64) * E2_) + tid;
    float4 acc = {0.f, 0.f, 0.f, 0.f};
    #pragma unroll 8
    for (int s = 0; s < 64; ++s) {
        float4 e4 = ep[(size_t)s * (E2_ / 4)];
        const float ws = wsm[s];
        acc.x = fmaf(ws, e4.x, acc.x);
        acc.y = fmaf(ws, e4.y, acc.y);
        acc.z = fmaf(ws, e4.z, acc.z);
        acc.w = fmaf(ws, e4.w, acc.w);
    }
    reinterpret_cast<float4*>(out_part + ((size_t)sc * B_ + b) * E2_)[tid] = acc;
}

__global__ __launch_bounds__(256) void attout_reduce_kernel(
        const float* __restrict__ out_part,  // (8, B, E2)
        float* __restrict__ out)             // (B, E2)
{
    const int idx = blockIdx.x * 256 + threadIdx.x;   // float4 index
    const int n4 = (B_ * E2_) / 4;
    const float4* p = reinterpret_cast<const float4*>(out_part);
    float4 r = p[idx];
    #pragma unroll
    for (int c = 1; c < 8; ++c) {
        float4 q = p[idx + c * n4];
        r.x += q.x; r.y += q.y; r.z += q.z; r.w += q.w;
    }
    reinterpret_cast<float4*>(out)[idx] = r;
}

// ---------------------------------------------------------------------------
extern "C" void kernel_launch(void* const* d_in, const int* in_sizes, int n_in,
                              void* d_out, int out_size, void* d_ws, size_t ws_size,
                              hipStream_t stream) {
    const float* dec  = (const float*)d_in[0];   // (B, D)
    const float* enc  = (const float*)d_in[1];   // (B, S, E2)
    const int*   mask = (const int*)d_in[2];     // (B, S)
    const float* w    = (const float*)d_in[3];   // (D, D+E2)
    const float* bias = (const float*)d_in[4];   // (D)
    const float* v    = (const float*)d_in[5];   // (D)
    float* out = (float*)d_out;                  // (B, 1, E2)

    // workspace layout
    float* t_buf    = (float*)d_ws;                      // B*D          f32
    float* att_part = t_buf + B_ * D_;                   // B*S*NTILES   f32
    float* wgt_buf  = att_part + B_ * S_ * NTILES;       // B*S          f32
    float* out_part = wgt_buf + B_ * S_;                 // 8*B*E2       f32
    unsigned short* web = (unsigned short*)(out_part + 8 * B_ * E2_); // D*E2 bf16

    conv_we_kernel<<<D_, 256, 0, stream>>>(w, web);
    dec_proj_kernel<<<D_, 256, 0, stream>>>(dec, w, bias, t_buf);
    energy_mfma_kernel<<<512, 512, 0, stream>>>(enc, web, t_buf, v, att_part);
    softmax_kernel<<<B_, 256, 0, stream>>>(att_part, mask, wgt_buf);
    attout_part_kernel<<<dim3(8, B_), 256, 0, stream>>>(wgt_buf, enc, out_part);
    attout_reduce_kernel<<<(B_ * E2_ / 4) / 256, 256, 0, stream>>>(out_part, out);
}

// Round 8
// 155.457 us; speedup vs baseline: 1.3018x; 1.3018x over previous
//
#include <hip/hip_runtime.h>
#include <hip/hip_bf16.h>
#include <math.h>

// Problem dims (fixed by the reference)
#define B_  64
#define S_  512
#define D_  1024
#define E2_ 1024
#define WROW (D_ + E2_)   // 2048, row stride of w_weight
#define NTILES 4          // D_ / BNE (256-wide n-tiles)

typedef __attribute__((ext_vector_type(8))) short bf16x8;
typedef __attribute__((ext_vector_type(4))) float f32x4;
typedef __attribute__((ext_vector_type(8))) unsigned short u16x8;

// round-to-nearest-even f32 -> bf16
__device__ __forceinline__ unsigned short f2bf(float f) {
    unsigned u = __float_as_uint(f);
    u = (u + 0x7FFFu + ((u >> 16) & 1u)) >> 16;
    return (unsigned short)u;
}

__device__ __forceinline__ void load_lds16(const void* g, void* l) {
    __builtin_amdgcn_global_load_lds(
        (__attribute__((address_space(1))) void*)(void*)g,
        (__attribute__((address_space(3))) void*)l,
        16, 0, 0);
}

// branch-free tanh via v_exp_f32: tanh(x) = sign(x)*(e^{2|x|}-1)/(e^{2|x|}+1)
__device__ __forceinline__ float fast_tanh(float x) {
    float ax = fminf(fabsf(x), 16.0f);                       // tanh(16)==1.0f
    float t  = __builtin_amdgcn_exp2f(ax * 2.8853900817779268f); // e^{2ax}
    float r  = (t - 1.0f) * __builtin_amdgcn_rcpf(t + 1.0f);
    return copysignf(r, x);
}

// ---------------------------------------------------------------------------
// Convert We = w[:, D_:] (strided in w) -> dense bf16 (D_ x E2_)
// ---------------------------------------------------------------------------
__global__ __launch_bounds__(256) void conv_we_kernel(
        const float* __restrict__ w, unsigned short* __restrict__ web)
{
    const int k = blockIdx.x;
    const int j = threadIdx.x * 4;
    float4 a = *reinterpret_cast<const float4*>(w + (size_t)k * WROW + D_ + j);
    ushort4 o;
    o.x = f2bf(a.x); o.y = f2bf(a.y); o.z = f2bf(a.z); o.w = f2bf(a.w);
    *reinterpret_cast<ushort4*>(web + (size_t)k * E2_ + j) = o;
}

// ---------------------------------------------------------------------------
// Kernel A: t[b][k] = sum_d dec[b,d] * W[k,d] + bias[k]   (Wd = w[:, :D]), f32
// ---------------------------------------------------------------------------
__global__ __launch_bounds__(256) void dec_proj_kernel(
        const float* __restrict__ dec,    // (B, D)
        const float* __restrict__ w,      // (D, 2048)
        const float* __restrict__ bias,   // (D)
        float* __restrict__ t)            // (B, D)
{
    __shared__ float wrow[D_];
    __shared__ float red[256];
    const int k = blockIdx.x;
    const int tid = threadIdx.x;

    const float* wr = w + (size_t)k * WROW;
    for (int i = tid; i < D_; i += 256) wrow[i] = wr[i];
    __syncthreads();

    const int b = tid >> 2;
    const int q = tid & 3;
    const float* dp = dec + b * D_ + q * 256;
    const float* wp = wrow + q * 256;
    float acc = 0.f;
    #pragma unroll 8
    for (int i = 0; i < 256; ++i) acc = fmaf(dp[i], wp[i], acc);
    red[tid] = acc;
    __syncthreads();
    if (q == 0) {
        float s = red[tid] + red[tid + 1] + red[tid + 2] + red[tid + 3];
        t[b * D_ + k] = s + bias[k];
    }
}

// ---------------------------------------------------------------------------
// Kernel B: 256x256 tile, BK=64, 8 waves (2 wm x 4 wn), 512 threads.
// FUSED f32->bf16 A conversion, SINK-PROOFED: per K-tile the A staging is
// split in two halves of 4x float4 (16 VGPR in flight); load-issue is pinned
// BEFORE the MFMA cluster with sched_barrier(0) so LLVM cannot sink the
// loads to their cvt+ds_write use (R7 failure: sunk loads serialized HBM
// latency on the critical path). Schedule per kt:
//   issueA(lo) + issueB(gload_lds) | SB | MFMA kk0 | SB |
//   writeA(lo)+issueA(hi)          | SB | MFMA kk1 | SB | writeA(hi) | bar
// LDS layout: logical (row r, byte kb) at phys r*128 + (kb^((r&7)<<4));
// A ds_write uses the same XOR on the write side (both-sides swizzle).
// XCD m-locality swizzle: 4 n-tile blocks of one m-tile -> same XCD.
// Fused epilogue: tanh + v-dot + cross-wave reduce -> att_part (B*S, 4).
// ---------------------------------------------------------------------------
#define BME 256
#define BNE 256
#define BKE 64
#define KT_ (E2_ / BKE)   // 16 K-tiles

__global__ __launch_bounds__(512, 2) void energy_mfma_kernel(
        const float* __restrict__ encf,           // (B*S, E2) f32
        const unsigned short* __restrict__ web,   // (D, E2) bf16
        const float* __restrict__ t,              // (B, D)
        const float* __restrict__ v,              // (D)
        float* __restrict__ att_part)             // (B*S, NTILES)
{
    __shared__ __align__(16) unsigned short As[2][BME * BKE];  // 2 x 32 KB
    __shared__ __align__(16) unsigned short Bs[2][BNE * BKE];  // 2 x 32 KB
    __shared__ float tv_s[BNE];
    __shared__ float vv_s[BNE];
    __shared__ float red[4][BME];

    // XCD m-locality swizzle: 512 blocks = 128 mblk x 4 ntile.
    const int g     = blockIdx.x;
    const int mblk  = (g & 7) + 8 * (g >> 5);
    const int ntile = (g >> 3) & 3;

    const int m0 = mblk * BME;
    const int n0 = ntile * BNE;
    const int b  = m0 >> 9;                 // 256-row tile never spans batches
    const int tid = threadIdx.x;
    const int w   = tid >> 6;               // wave 0..7
    const int l   = tid & 63;
    const int wm  = w >> 2;                 // wave row (0..1) -> 128 m-rows
    const int wn  = w & 3;                  // wave col (0..3) -> 64 n-cols

    if (tid < BNE) {
        tv_s[tid] = t[b * D_ + n0 + tid];
        vv_s[tid] = v[n0 + tid];
    }

    // --- A reg-staging geometry (f32 source, coalesced) ---
    // half h, i in 0..3: row = (h*4+i)*32 + (tid>>4), col = (tid&15)*4 f32
    const int arow0 = tid >> 4;              // 0..31; row&7 == arow0&7
    const int acolb = (tid & 15) * 8;        // byte col in bf16 row
    const int aswz  = (arow0 & 7) << 4;
    const float* gAf = encf + (size_t)m0 * E2_;

    // --- B staging source address (inverse-swizzled global, gload_lds) ---
    const int lr8 = l >> 3;
    const int lk  = 8 * ((l & 7) ^ lr8);
    const unsigned short* gB = web + (size_t)n0 * E2_;

    // --- frag read offsets ---
    const int rA = wm * 128 + (l & 15);
    const int rB = wn * 64 + (l & 15);
    const int kswz = (l & 7) << 4;
    const int khi  = (l >> 4) << 4;

    f32x4 acc[8][4] = {};
    float4 av[4];                            // one half in flight (16 VGPR)

    auto issueA4 = [&](int kt, int h) {
        const int k0 = kt * BKE;
        #pragma unroll
        for (int i = 0; i < 4; ++i) {
            const int row = (h * 4 + i) * 32 + arow0;
            av[i] = *reinterpret_cast<const float4*>(
                gAf + (size_t)row * E2_ + k0 + (tid & 15) * 4);
        }
    };
    auto writeA4 = [&](int bf, int h) {
        #pragma unroll
        for (int i = 0; i < 4; ++i) {
            const int row = (h * 4 + i) * 32 + arow0;
            ushort4 o;
            o.x = f2bf(av[i].x); o.y = f2bf(av[i].y);
            o.z = f2bf(av[i].z); o.w = f2bf(av[i].w);
            *reinterpret_cast<ushort4*>(
                (char*)As[bf] + row * 128 + (acolb ^ aswz)) = o;
        }
    };
    auto issueB = [&](int bf, int kt) {
        const int k0 = kt * BKE;
        #pragma unroll
        for (int r = 0; r < 4; ++r) {
            const int c = r * 8 + w;              // chunk 0..31
            const int row = c * 8 + lr8;          // 0..255
            load_lds16(gB + (size_t)row * E2_ + k0 + lk,
                       (char*)Bs[bf] + c * 1024);
        }
    };

    // prologue: stage tile 0 (serial, once)
    issueA4(0, 0); writeA4(0, 0);
    issueA4(0, 1); writeA4(0, 1);
    issueB(0, 0);
    __syncthreads();

    for (int kt = 0; kt < KT_; ++kt) {
        const int cur = kt & 1;
        const int nxt = cur ^ 1;
        const bool pre = (kt + 1 < KT_);

        if (pre) { issueA4(kt + 1, 0); issueB(nxt, kt + 1); }
        __builtin_amdgcn_sched_barrier(0);   // pin load issue ABOVE compute

        #pragma unroll
        for (int kk = 0; kk < 2; ++kk) {
            const int kb = (kk * 64 + khi) ^ kswz;
            bf16x8 a[8], bb[4];
            #pragma unroll
            for (int mi = 0; mi < 8; ++mi)
                a[mi] = *reinterpret_cast<const bf16x8*>(
                    (const char*)As[cur] + (rA + mi * 16) * 128 + kb);
            #pragma unroll
            for (int ni = 0; ni < 4; ++ni)
                bb[ni] = *reinterpret_cast<const bf16x8*>(
                    (const char*)Bs[cur] + (rB + ni * 16) * 128 + kb);
            __builtin_amdgcn_s_setprio(1);
            #pragma unroll
            for (int mi = 0; mi < 8; ++mi)
                #pragma unroll
                for (int ni = 0; ni < 4; ++ni)
                    acc[mi][ni] = __builtin_amdgcn_mfma_f32_16x16x32_bf16(
                        a[mi], bb[ni], acc[mi][ni], 0, 0, 0);
            __builtin_amdgcn_s_setprio(0);

            __builtin_amdgcn_sched_barrier(0);
            if (kk == 0) {
                // lo loads retired under kk0's MFMA; cvt+write lo, issue hi
                if (pre) { writeA4(nxt, 0); issueA4(kt + 1, 1); }
                __builtin_amdgcn_sched_barrier(0);
            }
        }

        if (pre) writeA4(nxt, 1);
        __syncthreads();   // drains gload_lds + ds_writes, orders buffer reuse
    }

    // --- epilogue: tanh + v-dot, reduce over n ---
    // D frag mapping: col = l&15, row = (l>>4)*4 + j  [m89-verified]
    #pragma unroll
    for (int mi = 0; mi < 8; ++mi) {
        float P[4] = {0.f, 0.f, 0.f, 0.f};
        #pragma unroll
        for (int ni = 0; ni < 4; ++ni) {
            const int nl = wn * 64 + ni * 16 + (l & 15);
            const float tvv = tv_s[nl];
            const float vvv = vv_s[nl];
            #pragma unroll
            for (int j = 0; j < 4; ++j) {
                float e = fast_tanh(acc[mi][ni][j] + tvv);
                P[j] = fmaf(e, vvv, P[j]);
            }
        }
        #pragma unroll
        for (int j = 0; j < 4; ++j) {
            float p = P[j];
            p += __shfl_xor(p, 1);
            p += __shfl_xor(p, 2);
            p += __shfl_xor(p, 4);
            p += __shfl_xor(p, 8);
            if ((l & 15) == 0)
                red[wn][wm * 128 + mi * 16 + (l >> 4) * 4 + j] = p;
        }
    }
    __syncthreads();
    if (tid < BME)
        att_part[(size_t)(m0 + tid) * NTILES + ntile] =
            (red[0][tid] + red[1][tid]) + (red[2][tid] + red[3][tid]);
}

// ---------------------------------------------------------------------------
// Kernel C: reduce partials + masked softmax over s per batch. One block per b.
// ---------------------------------------------------------------------------
__global__ __launch_bounds__(256) void softmax_kernel(
        const float* __restrict__ att_part,  // (B*S, NTILES)
        const int* __restrict__ mask,        // (B, S)
        float* __restrict__ wout)            // (B, S)
{
    __shared__ float red[256];
    const int b = blockIdx.x;
    const int tid = threadIdx.x;

    float x0 = 0.f, x1 = 0.f;
    #pragma unroll
    for (int p = 0; p < NTILES; ++p) {
        x0 += att_part[(size_t)(b * S_ + tid) * NTILES + p];
        x1 += att_part[(size_t)(b * S_ + 256 + tid) * NTILES + p];
    }
    bool m0v = (mask[b * S_ + tid] != 0);
    bool m1v = (mask[b * S_ + 256 + tid] != 0);
    if (!m0v) x0 = -INFINITY;
    if (!m1v) x1 = -INFINITY;

    float m = fmaxf(x0, x1);
    red[tid] = m;
    __syncthreads();
    for (int o = 128; o > 0; o >>= 1) {
        if (tid < o) red[tid] = fmaxf(red[tid], red[tid + o]);
        __syncthreads();
    }
    m = red[0];
    __syncthreads();

    float e0 = m0v ? expf(x0 - m) : 0.f;
    float e1 = m1v ? expf(x1 - m) : 0.f;
    red[tid] = e0 + e1;
    __syncthreads();
    for (int o = 128; o > 0; o >>= 1) {
        if (tid < o) red[tid] += red[tid + o];
        __syncthreads();
    }
    const float inv = 1.f / red[0];
    wout[b * S_ + tid] = e0 * inv;
    wout[b * S_ + 256 + tid] = e1 * inv;
}

// ---------------------------------------------------------------------------
// Kernel D: out_part[sc][b][e] = sum_{s in chunk sc} wgt[b,s]*enc[b,s,e]
// f32 enc, float4/lane, 8 s-chunks of 64 for occupancy; tiny reduce after.
// ---------------------------------------------------------------------------
__global__ __launch_bounds__(256) void attout_part_kernel(
        const float* __restrict__ wgt,    // (B, S)
        const float* __restrict__ enc,    // (B, S, E2) f32
        float* __restrict__ out_part)     // (8, B, E2)
{
    __shared__ float wsm[64];
    const int b  = blockIdx.y;
    const int sc = blockIdx.x;            // 0..7
    const int tid = threadIdx.x;          // e4 index, covers E2 = 256*4
    if (tid < 64) wsm[tid] = wgt[b * S_ + sc * 64 + tid];
    __syncthreads();

    const float4* ep = reinterpret_cast<const float4*>(
        enc + ((size_t)b * S_ + sc * 64) * E2_) + tid;
    float4 acc = {0.f, 0.f, 0.f, 0.f};
    #pragma unroll 8
    for (int s = 0; s < 64; ++s) {
        float4 e4 = ep[(size_t)s * (E2_ / 4)];
        const float ws = wsm[s];
        acc.x = fmaf(ws, e4.x, acc.x);
        acc.y = fmaf(ws, e4.y, acc.y);
        acc.z = fmaf(ws, e4.z, acc.z);
        acc.w = fmaf(ws, e4.w, acc.w);
    }
    reinterpret_cast<float4*>(out_part + ((size_t)sc * B_ + b) * E2_)[tid] = acc;
}

__global__ __launch_bounds__(256) void attout_reduce_kernel(
        const float* __restrict__ out_part,  // (8, B, E2)
        float* __restrict__ out)             // (B, E2)
{
    const int idx = blockIdx.x * 256 + threadIdx.x;   // float4 index
    const int n4 = (B_ * E2_) / 4;
    const float4* p = reinterpret_cast<const float4*>(out_part);
    float4 r = p[idx];
    #pragma unroll
    for (int c = 1; c < 8; ++c) {
        float4 q = p[idx + c * n4];
        r.x += q.x; r.y += q.y; r.z += q.z; r.w += q.w;
    }
    reinterpret_cast<float4*>(out)[idx] = r;
}

// ---------------------------------------------------------------------------
extern "C" void kernel_launch(void* const* d_in, const int* in_sizes, int n_in,
                              void* d_out, int out_size, void* d_ws, size_t ws_size,
                              hipStream_t stream) {
    const float* dec  = (const float*)d_in[0];   // (B, D)
    const float* enc  = (const float*)d_in[1];   // (B, S, E2)
    const int*   mask = (const int*)d_in[2];     // (B, S)
    const float* w    = (const float*)d_in[3];   // (D, D+E2)
    const float* bias = (const float*)d_in[4];   // (D)
    const float* v    = (const float*)d_in[5];   // (D)
    float* out = (float*)d_out;                  // (B, 1, E2)

    // workspace layout
    float* t_buf    = (float*)d_ws;                      // B*D          f32
    float* att_part = t_buf + B_ * D_;                   // B*S*NTILES   f32
    float* wgt_buf  = att_part + B_ * S_ * NTILES;       // B*S          f32
    float* out_part = wgt_buf + B_ * S_;                 // 8*B*E2       f32
    unsigned short* web = (unsigned short*)(out_part + 8 * B_ * E2_); // D*E2 bf16

    conv_we_kernel<<<D_, 256, 0, stream>>>(w, web);
    dec_proj_kernel<<<D_, 256, 0, stream>>>(dec, w, bias, t_buf);
    energy_mfma_kernel<<<512, 512, 0, stream>>>(enc, web, t_buf, v, att_part);
    softmax_kernel<<<B_, 256, 0, stream>>>(att_part, mask, wgt_buf);
    attout_part_kernel<<<dim3(8, B_), 256, 0, stream>>>(wgt_buf, enc, out_part);
    attout_reduce_kernel<<<(B_ * E2_ / 4) / 256, 256, 0, stream>>>(out_part, out);
}